// Round 3
// baseline (115.279 us; speedup 1.0000x reference)
//
#include <hip/hip_runtime.h>

#define NCLS 80
#define NA 5
#define HW 1600          // 40*40
#define GW 40
#define NBOX 8000        // NA*HW  (divisible by 64)
#define CONF_THR 0.5f
#define IOU_THR 0.45f
#define STRIDE_F 32.0f   // 1280/40
#define CAP 128          // per-class list capacity (expected max ~75)

// workspace layout (4-byte elements): only 6 arrays, 192 KB
#define WS_BX 0
#define WS_BY (NBOX)
#define WS_BW (2*NBOX)
#define WS_BH (3*NBOX)
#define WS_CF (4*NBOX)
#define WS_CLS (5*NBOX)  // int

__device__ __forceinline__ float sigmoidf_(float t) {
  return 1.0f / (1.0f + expf(-t));
}

// K1: decode + argmax class; zero the whole output (coalesced).
__global__ void k_decode(const float* __restrict__ x,
                         const float* __restrict__ anchors,
                         float* __restrict__ ws,
                         float* __restrict__ out) {
  int n = blockIdx.x * blockDim.x + threadIdx.x;
  if (n >= NBOX) return;
  int a = n / HW, r = n - a * HW;
  int gi = r / GW, gj = r - gi * GW;
  const float* base = x + (size_t)a * (5 + NCLS) * HW + r;

  float t0 = base[0];
  float t1 = base[HW];
  float t2 = base[2 * HW];
  float t3 = base[3 * HW];
  float t4 = base[4 * HW];
  float ax = anchors[2 * a], ay = anchors[2 * a + 1];

  float cx = (sigmoidf_(t0) + (float)gj) * STRIDE_F;
  float cy = (sigmoidf_(t1) + (float)gi) * STRIDE_F;
  float bw = (expf(t2) * ax) * STRIDE_F;
  float bh = (expf(t3) * ay) * STRIDE_F;
  float cf = sigmoidf_(t4);

  // argmax over raw class logits (first-index tie-break)
  float best = base[5 * HW];
  int bi = 0;
#pragma unroll
  for (int c = 1; c < NCLS; ++c) {
    float v = base[(5 + c) * HW];
    if (v > best) { best = v; bi = c; }
  }

  ws[WS_BX + n] = cx;  ws[WS_BY + n] = cy;
  ws[WS_BW + n] = bw;  ws[WS_BH + n] = bh;
  ws[WS_CF + n] = cf;
  ((int*)(ws + WS_CLS))[n] = bi;

  // zero entire output [8000*6 boxes | 8000 keep] with coalesced strided stores
#pragma unroll
  for (int j = 0; j < 7; ++j) out[j * NBOX + n] = 0.0f;
}

// K2: one wave per class. Ballot-collect class members (index-ascending),
// stable rank by (conf desc, pos asc), register-resident greedy NMS, write kept.
__global__ void k_nms(const float* __restrict__ ws, float* __restrict__ out) {
  __shared__ float sconf[CAP];
  __shared__ int   slidx[CAP];
  __shared__ int   ssort[CAP];
  __shared__ float sx1[CAP], sy1[CAP], sx2[CAP], sy2[CAP], sar[CAP];

  int c = blockIdx.x, lane = threadIdx.x;
  const int*   cls = (const int*)(ws + WS_CLS);
  const float* cfp = ws + WS_CF;

  // collect members of class c in ascending original-index order
  int count = 0;
  for (int base_i = 0; base_i < NBOX; base_i += 64) {
    int i = base_i + lane;
    float cfi = cfp[i];
    int ci = cls[i];
    bool pred = (cfi > CONF_THR) && (ci == c);
    unsigned long long bal = __ballot(pred);
    if (pred) {
      int pos = count + __popcll(bal & ((1ull << lane) - 1ull));
      if (pos < CAP) { sconf[pos] = cfi; slidx[pos] = i; }
    }
    count += (int)__popcll(bal);
  }
  int n = count > CAP ? CAP : count;
  __syncthreads();
  if (n <= 0) return;

  // stable rank: conf desc, list-position (== original index) asc
  for (int p = lane; p < n; p += 64) {
    float cp = sconf[p]; int ip = slidx[p]; int rk = 0;
    for (int q = 0; q < n; ++q) {
      float cq = sconf[q];
      if (cq > cp || (cq == cp && q < p)) ++rk;
    }
    ssort[rk] = ip;
  }
  __syncthreads();

  // gather sorted boxes; corners/area recomputed bit-identically to reference
  int   gidx[2] = {-1, -1};
  float gbx[2], gby[2], gbw[2], gbh[2], gcf[2];
  float gx1[2], gy1[2], gx2[2], gy2[2], gar[2];
#pragma unroll
  for (int s = 0; s < 2; ++s) {
    int q = lane + 64 * s;
    gx1[s] = gy1[s] = gx2[s] = gy2[s] = gar[s] = 0.0f;
    if (q < n) {
      int i = ssort[q]; gidx[s] = i;
      float bx = ws[WS_BX + i], by = ws[WS_BY + i];
      float bw = ws[WS_BW + i], bh = ws[WS_BH + i];
      gbx[s] = bx; gby[s] = by; gbw[s] = bw; gbh[s] = bh;
      gcf[s] = ws[WS_CF + i];
      gx1[s] = bx - bw * 0.5f; gy1[s] = by - bh * 0.5f;
      gx2[s] = bx + bw * 0.5f; gy2[s] = by + bh * 0.5f;
      gar[s] = fmaxf(gx2[s] - gx1[s], 0.0f) * fmaxf(gy2[s] - gy1[s], 0.0f);
      sx1[q] = gx1[s]; sy1[q] = gy1[s];
      sx2[q] = gx2[s]; sy2[q] = gy2[s]; sar[q] = gar[s];
    }
  }
  __syncthreads();

  // serial greedy scan; suppression masks are wave-uniform registers
  unsigned long long sup0 = 0ull, sup1 = 0ull;
  for (int p = 0; p < n; ++p) {
    unsigned long long bit = (p < 64) ? (sup0 >> p) : (sup1 >> (p - 64));
    if (bit & 1ull) continue;
    float px1 = sx1[p], py1 = sy1[p], px2 = sx2[p], py2 = sy2[p], pa = sar[p];
    bool pr0 = false, pr1 = false;
    {
      int q = lane;
      if (q > p && q < n) {
        float ix1 = fmaxf(px1, gx1[0]), iy1 = fmaxf(py1, gy1[0]);
        float ix2 = fminf(px2, gx2[0]), iy2 = fminf(py2, gy2[0]);
        float inter = fmaxf(ix2 - ix1, 0.0f) * fmaxf(iy2 - iy1, 0.0f);
        float iou = inter / (pa + gar[0] - inter + 1e-9f);
        pr0 = iou > IOU_THR;
      }
      q = lane + 64;
      if (q > p && q < n) {
        float ix1 = fmaxf(px1, gx1[1]), iy1 = fmaxf(py1, gy1[1]);
        float ix2 = fminf(px2, gx2[1]), iy2 = fminf(py2, gy2[1]);
        float inter = fmaxf(ix2 - ix1, 0.0f) * fmaxf(iy2 - iy1, 0.0f);
        float iou = inter / (pa + gar[1] - inter + 1e-9f);
        pr1 = iou > IOU_THR;
      }
    }
    sup0 |= __ballot(pr0);
    sup1 |= __ballot(pr1);
  }

  // write kept boxes (everything else already zeroed by k_decode)
#pragma unroll
  for (int s = 0; s < 2; ++s) {
    int q = lane + 64 * s;
    if (q < n) {
      unsigned long long m = s ? sup1 : sup0;
      if (!((m >> lane) & 1ull)) {
        int i = gidx[s];
        float* o = out + (size_t)i * 6;
        o[0] = gbx[s]; o[1] = gby[s]; o[2] = gbw[s]; o[3] = gbh[s];
        o[4] = gcf[s]; o[5] = (float)c;
        out[6 * NBOX + i] = 1.0f;
      }
    }
  }
}

extern "C" void kernel_launch(void* const* d_in, const int* in_sizes, int n_in,
                              void* d_out, int out_size, void* d_ws, size_t ws_size,
                              hipStream_t stream) {
  const float* x = (const float*)d_in[0];
  const float* anchors = (const float*)d_in[1];
  float* out = (float*)d_out;
  float* ws = (float*)d_ws;

  k_decode<<<(NBOX + 255) / 256, 256, 0, stream>>>(x, anchors, ws, out);
  k_nms<<<NCLS, 64, 0, stream>>>(ws, out);
}